// Round 2
// baseline (295.543 us; speedup 1.0000x reference)
//
#include <hip/hip_runtime.h>
#include <stdint.h>

#define Bsz   16384
#define Tt    79
#define Hh    256
#define Dd    256
#define KP    288    // padded K: 256 h-cols + 3 x rows + 1 bias row + 28 zero pad
#define LROW  296    // LDS row stride in bf16 elements (592 B)
#define NTILE 64     // batch rows per block

typedef __attribute__((ext_vector_type(8))) short  short8;
typedef __attribute__((ext_vector_type(4))) float  float4_;

__device__ __forceinline__ unsigned short f2bf(float f){
  unsigned u = __float_as_uint(f);
  u += 0x7fffu + ((u >> 16) & 1u);      // RNE
  return (unsigned short)(u >> 16);
}
__device__ __forceinline__ unsigned pk2(float a, float b){
  return (unsigned)f2bf(a) | ((unsigned)f2bf(b) << 16);
}

__global__ void build_tables(const float* __restrict__ W_in,
                             const float* __restrict__ U,
                             const float* __restrict__ b_rnn,
                             const float* __restrict__ W_d,
                             const float* __restrict__ b_d,
                             unsigned short* __restrict__ Ut,
                             unsigned short* __restrict__ Wdt){
  const int TBL = 256 * KP;
  int idx = blockIdx.x * 256 + threadIdx.x;
  if (idx >= 2 * TBL) return;
  int tb  = idx / TBL;
  int rem = idx - tb * TBL;
  int m = rem / KP;
  int k = rem - m * KP;
  float v = 0.f;
  if (tb == 0){
    if      (k < 256) v = U[k * 256 + m];
    else if (k < 259) v = W_in[(k - 256) * 256 + m];
    else if (k == 259) v = b_rnn[m];
  } else {
    if      (k < 256) v = W_d[k * 256 + m];
    else if (k == 259) v = b_d[m];
  }
  unsigned short o = f2bf(v);
  if (tb == 0) Ut[rem] = o; else Wdt[rem] = o;
}

// ---- named A-fragment machinery: 8 mt x 9 kt = 72 short8, pinned in VGPRs ----
#define DECL_A(mt) short8 A##mt##_0,A##mt##_1,A##mt##_2,A##mt##_3,A##mt##_4, \
                         A##mt##_5,A##mt##_6,A##mt##_7,A##mt##_8;

#define LOAD_A(mt) { const unsigned short* p = Ut + (wm*128 + (mt)*16 + ln)*KP + quad*8; \
  A##mt##_0 = *(const short8*)(p       ); \
  A##mt##_1 = *(const short8*)(p +  32 ); \
  A##mt##_2 = *(const short8*)(p +  64 ); \
  A##mt##_3 = *(const short8*)(p +  96 ); \
  A##mt##_4 = *(const short8*)(p + 128 ); \
  A##mt##_5 = *(const short8*)(p + 160 ); \
  A##mt##_6 = *(const short8*)(p + 192 ); \
  A##mt##_7 = *(const short8*)(p + 224 ); \
  A##mt##_8 = *(const short8*)(p + 256 ); }

#define PIN_A(mt) asm volatile("" : "+v"(A##mt##_0), "+v"(A##mt##_1), "+v"(A##mt##_2), \
  "+v"(A##mt##_3), "+v"(A##mt##_4), "+v"(A##mt##_5), "+v"(A##mt##_6), \
  "+v"(A##mt##_7), "+v"(A##mt##_8));

#define MFMA_KT0 { \
  short8 b0 = *(const short8*)&hb[rb0*LROW + qoff]; \
  short8 b1 = *(const short8*)&hb[rb1*LROW + qoff]; \
  acc[0][0]=__builtin_amdgcn_mfma_f32_16x16x32_bf16(A0_0,b0,zz,0,0,0); \
  acc[0][1]=__builtin_amdgcn_mfma_f32_16x16x32_bf16(A0_0,b1,zz,0,0,0); \
  acc[1][0]=__builtin_amdgcn_mfma_f32_16x16x32_bf16(A1_0,b0,zz,0,0,0); \
  acc[1][1]=__builtin_amdgcn_mfma_f32_16x16x32_bf16(A1_0,b1,zz,0,0,0); \
  acc[2][0]=__builtin_amdgcn_mfma_f32_16x16x32_bf16(A2_0,b0,zz,0,0,0); \
  acc[2][1]=__builtin_amdgcn_mfma_f32_16x16x32_bf16(A2_0,b1,zz,0,0,0); \
  acc[3][0]=__builtin_amdgcn_mfma_f32_16x16x32_bf16(A3_0,b0,zz,0,0,0); \
  acc[3][1]=__builtin_amdgcn_mfma_f32_16x16x32_bf16(A3_0,b1,zz,0,0,0); \
  acc[4][0]=__builtin_amdgcn_mfma_f32_16x16x32_bf16(A4_0,b0,zz,0,0,0); \
  acc[4][1]=__builtin_amdgcn_mfma_f32_16x16x32_bf16(A4_0,b1,zz,0,0,0); \
  acc[5][0]=__builtin_amdgcn_mfma_f32_16x16x32_bf16(A5_0,b0,zz,0,0,0); \
  acc[5][1]=__builtin_amdgcn_mfma_f32_16x16x32_bf16(A5_0,b1,zz,0,0,0); \
  acc[6][0]=__builtin_amdgcn_mfma_f32_16x16x32_bf16(A6_0,b0,zz,0,0,0); \
  acc[6][1]=__builtin_amdgcn_mfma_f32_16x16x32_bf16(A6_0,b1,zz,0,0,0); \
  acc[7][0]=__builtin_amdgcn_mfma_f32_16x16x32_bf16(A7_0,b0,zz,0,0,0); \
  acc[7][1]=__builtin_amdgcn_mfma_f32_16x16x32_bf16(A7_0,b1,zz,0,0,0); }

#define MFMA_KT(kt) { \
  short8 b0 = *(const short8*)&hb[rb0*LROW + (kt)*32 + qoff]; \
  short8 b1 = *(const short8*)&hb[rb1*LROW + (kt)*32 + qoff]; \
  acc[0][0]=__builtin_amdgcn_mfma_f32_16x16x32_bf16(A0_##kt,b0,acc[0][0],0,0,0); \
  acc[0][1]=__builtin_amdgcn_mfma_f32_16x16x32_bf16(A0_##kt,b1,acc[0][1],0,0,0); \
  acc[1][0]=__builtin_amdgcn_mfma_f32_16x16x32_bf16(A1_##kt,b0,acc[1][0],0,0,0); \
  acc[1][1]=__builtin_amdgcn_mfma_f32_16x16x32_bf16(A1_##kt,b1,acc[1][1],0,0,0); \
  acc[2][0]=__builtin_amdgcn_mfma_f32_16x16x32_bf16(A2_##kt,b0,acc[2][0],0,0,0); \
  acc[2][1]=__builtin_amdgcn_mfma_f32_16x16x32_bf16(A2_##kt,b1,acc[2][1],0,0,0); \
  acc[3][0]=__builtin_amdgcn_mfma_f32_16x16x32_bf16(A3_##kt,b0,acc[3][0],0,0,0); \
  acc[3][1]=__builtin_amdgcn_mfma_f32_16x16x32_bf16(A3_##kt,b1,acc[3][1],0,0,0); \
  acc[4][0]=__builtin_amdgcn_mfma_f32_16x16x32_bf16(A4_##kt,b0,acc[4][0],0,0,0); \
  acc[4][1]=__builtin_amdgcn_mfma_f32_16x16x32_bf16(A4_##kt,b1,acc[4][1],0,0,0); \
  acc[5][0]=__builtin_amdgcn_mfma_f32_16x16x32_bf16(A5_##kt,b0,acc[5][0],0,0,0); \
  acc[5][1]=__builtin_amdgcn_mfma_f32_16x16x32_bf16(A5_##kt,b1,acc[5][1],0,0,0); \
  acc[6][0]=__builtin_amdgcn_mfma_f32_16x16x32_bf16(A6_##kt,b0,acc[6][0],0,0,0); \
  acc[6][1]=__builtin_amdgcn_mfma_f32_16x16x32_bf16(A6_##kt,b1,acc[6][1],0,0,0); \
  acc[7][0]=__builtin_amdgcn_mfma_f32_16x16x32_bf16(A7_##kt,b0,acc[7][0],0,0,0); \
  acc[7][1]=__builtin_amdgcn_mfma_f32_16x16x32_bf16(A7_##kt,b1,acc[7][1],0,0,0); }

__global__ __launch_bounds__(256, 1) void rnn_main(
    const float* __restrict__ x0,
    const float* __restrict__ x1,
    const float* __restrict__ x2,
    const unsigned short* __restrict__ Ut,
    const unsigned short* __restrict__ Wdt,
    float* __restrict__ out){
  __shared__ __align__(16) short hbuf[2][NTILE * LROW];

  const int tid  = threadIdx.x;
  const int lane = tid & 63;
  const int wave = tid >> 6;
  const int wm   = wave >> 1;   // m-half 0/1
  const int wn   = wave & 1;    // n-half 0/1
  const int quad = lane >> 4;
  const int ln   = lane & 15;
  const int qoff = quad * 8;
  const int bbase = blockIdx.x * NTILE;
  const int rb0 = wn * 32 + ln;
  const int rb1 = rb0 + 16;

  // ---- zero both LDS buffers (h0 = 0, pad rows = 0) ----
  {
    int4* p = (int4*)&hbuf[0][0];
    const int tot = 2 * NTILE * LROW * 2 / 16;
    int4 z = make_int4(0, 0, 0, 0);
    for (int i = tid; i < tot; i += 256) p[i] = z;
  }
  __syncthreads();

  // bias row (k=259) = 1.0 bf16 in BOTH buffers (never overwritten)
  if (tid < NTILE){
    hbuf[0][tid * LROW + 259] = (short)0x3F80;
    hbuf[1][tid * LROW + 259] = (short)0x3F80;
  }

  // x rows for step t=0 (original time index T-1) into buf 0
  const bool stager = (wm == 0) && (lane < 32);
  const int  sn  = wn * 32 + lane;
  const int  sgb = bbase + sn;
  if (stager){
    int tr = Tt - 1;
    float a = x0[sgb * Tt + tr];
    float b = x1[sgb * Tt + tr];
    float c = x2[sgb * Tt + tr];
    *(unsigned*)&hbuf[0][sn * LROW + 256] = pk2(a, b);
    hbuf[0][sn * LROW + 258] = (short)f2bf(c);
  }

  // ---- preload A fragments (U^T + folded W_in/b_rnn): 72 short8 ----
  DECL_A(0) DECL_A(1) DECL_A(2) DECL_A(3)
  DECL_A(4) DECL_A(5) DECL_A(6) DECL_A(7)
  LOAD_A(0) LOAD_A(1) LOAD_A(2) LOAD_A(3)
  LOAD_A(4) LOAD_A(5) LOAD_A(6) LOAD_A(7)

  __syncthreads();

  const float4_ zz = {0.f, 0.f, 0.f, 0.f};
  float4_ acc[8][2];

  // ---- 79 recurrence steps, ONE barrier each (double-buffered h) ----
  #pragma unroll 1
  for (int t = 0; t < Tt; ++t){
    // pin A fragments as loop-carried register values (defeats remat/reload)
    PIN_A(0) PIN_A(1) PIN_A(2) PIN_A(3)
    PIN_A(4) PIN_A(5) PIN_A(6) PIN_A(7)

    // prefetch x for step t+1
    float xa = 0.f, xb = 0.f, xc = 0.f;
    if (stager && t < Tt - 1){
      int tr = Tt - 2 - t;
      xa = x0[sgb * Tt + tr];
      xb = x1[sgb * Tt + tr];
      xc = x2[sgb * Tt + tr];
    }

    const short* hb = &hbuf[t & 1][0];
    short*       hw = &hbuf[(t + 1) & 1][0];

    MFMA_KT0
    MFMA_KT(1) MFMA_KT(2) MFMA_KT(3) MFMA_KT(4)
    MFMA_KT(5) MFMA_KT(6) MFMA_KT(7) MFMA_KT(8)

    // relu + pack, write h(t+1) into the OTHER buffer (no read/write hazard)
    #pragma unroll
    for (int mt = 0; mt < 8; ++mt){
      #pragma unroll
      for (int nt = 0; nt < 2; ++nt){
        float4_ v = acc[mt][nt];
        uint2 w;
        w.x = pk2(fmaxf(v[0], 0.f), fmaxf(v[1], 0.f));
        w.y = pk2(fmaxf(v[2], 0.f), fmaxf(v[3], 0.f));
        int n = wn * 32 + nt * 16 + ln;
        int m = wm * 128 + mt * 16 + quad * 4;
        *(uint2*)&hw[n * LROW + m] = w;
      }
    }
    if (stager && t < Tt - 1){
      *(unsigned*)&hw[sn * LROW + 256] = pk2(xa, xb);
      hw[sn * LROW + 258] = (short)f2bf(xc);
    }

    __syncthreads();   // h(t+1)/x(t+1) visible; next step reads other buffer
  }

  // ---- epilogue: out^T = W_d^T h^T + b_d; final h is in buf[Tt&1] = buf[1] ----
  const short* hb = &hbuf[Tt & 1][0];
  float4_ oacc[8][2];
  #pragma unroll
  for (int kt = 0; kt < 9; ++kt){
    short8 wf[8];
    #pragma unroll
    for (int mt = 0; mt < 8; ++mt){
      int m = wm * 128 + mt * 16 + ln;
      wf[mt] = *(const short8*)(Wdt + m * KP + kt * 32 + qoff);
    }
    short8 b0 = *(const short8*)&hb[rb0 * LROW + kt * 32 + qoff];
    short8 b1 = *(const short8*)&hb[rb1 * LROW + kt * 32 + qoff];
    #pragma unroll
    for (int mt = 0; mt < 8; ++mt){
      if (kt == 0){
        oacc[mt][0] = __builtin_amdgcn_mfma_f32_16x16x32_bf16(wf[mt], b0, zz, 0, 0, 0);
        oacc[mt][1] = __builtin_amdgcn_mfma_f32_16x16x32_bf16(wf[mt], b1, zz, 0, 0, 0);
      } else {
        oacc[mt][0] = __builtin_amdgcn_mfma_f32_16x16x32_bf16(wf[mt], b0, oacc[mt][0], 0, 0, 0);
        oacc[mt][1] = __builtin_amdgcn_mfma_f32_16x16x32_bf16(wf[mt], b1, oacc[mt][1], 0, 0, 0);
      }
    }
  }

  #pragma unroll
  for (int mt = 0; mt < 8; ++mt){
    #pragma unroll
    for (int nt = 0; nt < 2; ++nt){
      int n = wn * 32 + nt * 16 + ln;
      int m = wm * 128 + mt * 16 + quad * 4;
      *(float4_*)&out[(bbase + n) * Dd + m] = oacc[mt][nt];
    }
  }
}

extern "C" void kernel_launch(void* const* d_in, const int* in_sizes, int n_in,
                              void* d_out, int out_size, void* d_ws, size_t ws_size,
                              hipStream_t stream){
  const float* x0    = (const float*)d_in[0];
  const float* x1    = (const float*)d_in[1];
  const float* x2    = (const float*)d_in[2];
  const float* W_in  = (const float*)d_in[3];
  const float* U     = (const float*)d_in[4];
  const float* b_rnn = (const float*)d_in[5];
  const float* W_d   = (const float*)d_in[6];
  const float* b_d   = (const float*)d_in[7];

  unsigned short* Ut  = (unsigned short*)d_ws;
  unsigned short* Wdt = Ut + 256 * KP;
  float* out = (float*)d_out;

  build_tables<<<(2 * 256 * KP + 255) / 256, 256, 0, stream>>>(W_in, U, b_rnn, W_d, b_d, Ut, Wdt);
  rnn_main<<<Bsz / NTILE, 256, 0, stream>>>(x0, x1, x2, Ut, Wdt, out);
}

// Round 3
// 214.455 us; speedup vs baseline: 1.3781x; 1.3781x over previous
//
#include <hip/hip_runtime.h>
#include <hip/hip_bf16.h>
#include <stdint.h>

#define Bsz   16384
#define Tt    79
#define Hh    256
#define Dd    256
#define KP    288    // padded K: 256 h-cols + 3 x rows + 1 bias row + 28 zero pad
#define LROW  296    // LDS row stride in bf16 elements (592 B)
#define NTILE 64     // batch rows per block
#define THR   512    // 8 waves: grid 4(m) x 2(n)

typedef __attribute__((ext_vector_type(8))) short  short8;
typedef __attribute__((ext_vector_type(4))) float  float4_;

__device__ __forceinline__ unsigned short f2bf(float f){
  unsigned u = __float_as_uint(f);
  u += 0x7fffu + ((u >> 16) & 1u);      // RNE
  return (unsigned short)(u >> 16);
}
__device__ __forceinline__ unsigned pk2(float a, float b){
  // v_cvt_pk_bf16_f32 on gfx950 (RNE), single VALU op
  __hip_bfloat162 h = __float22bfloat162_rn(make_float2(a, b));
  return *(unsigned*)&h;
}

__global__ void build_tables(const float* __restrict__ W_in,
                             const float* __restrict__ U,
                             const float* __restrict__ b_rnn,
                             const float* __restrict__ W_d,
                             const float* __restrict__ b_d,
                             unsigned short* __restrict__ Ut,
                             unsigned short* __restrict__ Wdt){
  const int TBL = 256 * KP;
  int idx = blockIdx.x * 256 + threadIdx.x;
  if (idx >= 2 * TBL) return;
  int tb  = idx / TBL;
  int rem = idx - tb * TBL;
  int m = rem / KP;
  int k = rem - m * KP;
  float v = 0.f;
  if (tb == 0){
    if      (k < 256) v = U[k * 256 + m];
    else if (k < 259) v = W_in[(k - 256) * 256 + m];
    else if (k == 259) v = b_rnn[m];
  } else {
    if      (k < 256) v = W_d[k * 256 + m];
    else if (k == 259) v = b_d[m];
  }
  unsigned short o = f2bf(v);
  if (tb == 0) Ut[rem] = o; else Wdt[rem] = o;
}

// 256 blocks x 512 threads (8 waves = 2/SIMD for latency hiding).
// Each block owns 64 batch rows; h^T (64 x 288 bf16, double-buffered) in LDS.
// Wave (wm 0..3, wn 0..1): 64 h-cols (4 MFMA tiles) x 32 batch rows (2 tiles).
// A-fragments (U^T + folded W_in/b_rnn): 36 x short8 = 144 VGPRs, loop-invariant.
__global__ __launch_bounds__(THR, 2) void rnn_main(
    const float* __restrict__ x0,
    const float* __restrict__ x1,
    const float* __restrict__ x2,
    const unsigned short* __restrict__ Ut,
    const unsigned short* __restrict__ Wdt,
    float* __restrict__ out){
  __shared__ __align__(16) short hbuf[2][NTILE * LROW];

  const int tid  = threadIdx.x;
  const int lane = tid & 63;
  const int wave = tid >> 6;
  const int wm   = wave >> 1;   // m-quarter 0..3
  const int wn   = wave & 1;    // n-half 0/1
  const int quad = lane >> 4;
  const int ln   = lane & 15;
  const int qoff = quad * 8;
  const int bbase = blockIdx.x * NTILE;
  const int rb0 = wn * 32 + ln;
  const int rb1 = rb0 + 16;

  // ---- zero both LDS buffers (h0 = 0, pad rows = 0) ----
  {
    int4* p = (int4*)&hbuf[0][0];
    const int tot = 2 * NTILE * LROW * 2 / 16;
    int4 z = make_int4(0, 0, 0, 0);
    for (int i = tid; i < tot; i += THR) p[i] = z;
  }
  __syncthreads();

  // bias row (k=259) = 1.0 bf16 in BOTH buffers (never overwritten)
  if (tid < NTILE){
    hbuf[0][tid * LROW + 259] = (short)0x3F80;
    hbuf[1][tid * LROW + 259] = (short)0x3F80;
  }

  // x rows for step t=0 (original time index T-1) into buf 0
  const bool stager = (wm == 0) && (lane < 32);
  const int  sn  = wn * 32 + (lane & 31);
  const int  sgb = bbase + sn;
  if (stager){
    int tr = Tt - 1;
    float a = x0[sgb * Tt + tr];
    float b = x1[sgb * Tt + tr];
    float c = x2[sgb * Tt + tr];
    *(unsigned*)&hbuf[0][sn * LROW + 256] = pk2(a, b);
    hbuf[0][sn * LROW + 258] = (short)f2bf(c);
  }

  // ---- preload A fragments: 4 mt x 9 kt = 36 short8 (144 VGPRs) ----
  short8 afr[4][9];
  #pragma unroll
  for (int mt = 0; mt < 4; ++mt){
    const unsigned short* p = Ut + (wm * 64 + mt * 16 + ln) * KP + qoff;
    #pragma unroll
    for (int kt = 0; kt < 9; ++kt){
      afr[mt][kt] = *(const short8*)(p + kt * 32);
    }
  }

  __syncthreads();

  const float4_ zz = {0.f, 0.f, 0.f, 0.f};
  float4_ acc[4][2];

  // ---- 79 recurrence steps, ONE barrier each (double-buffered h) ----
  #pragma unroll 1
  for (int t = 0; t < Tt; ++t){
    // prefetch x for step t+1 (latency hidden under the K-loop)
    float xa = 0.f, xb = 0.f, xc = 0.f;
    if (stager && t < Tt - 1){
      int tr = Tt - 2 - t;
      xa = x0[sgb * Tt + tr];
      xb = x1[sgb * Tt + tr];
      xc = x2[sgb * Tt + tr];
    }

    const short* hb = &hbuf[t & 1][0];
    short*       hw = &hbuf[(t + 1) & 1][0];

    #pragma unroll
    for (int kt = 0; kt < 9; ++kt){
      short8 b0 = *(const short8*)&hb[rb0 * LROW + kt * 32 + qoff];
      short8 b1 = *(const short8*)&hb[rb1 * LROW + kt * 32 + qoff];
      #pragma unroll
      for (int mt = 0; mt < 4; ++mt){
        if (kt == 0){
          acc[mt][0] = __builtin_amdgcn_mfma_f32_16x16x32_bf16(afr[mt][0], b0, zz, 0, 0, 0);
          acc[mt][1] = __builtin_amdgcn_mfma_f32_16x16x32_bf16(afr[mt][0], b1, zz, 0, 0, 0);
        } else {
          acc[mt][0] = __builtin_amdgcn_mfma_f32_16x16x32_bf16(afr[mt][kt], b0, acc[mt][0], 0, 0, 0);
          acc[mt][1] = __builtin_amdgcn_mfma_f32_16x16x32_bf16(afr[mt][kt], b1, acc[mt][1], 0, 0, 0);
        }
      }
    }

    // relu + pack (v_cvt_pk_bf16_f32), write h(t+1) into the OTHER buffer
    #pragma unroll
    for (int mt = 0; mt < 4; ++mt){
      #pragma unroll
      for (int nt = 0; nt < 2; ++nt){
        float4_ v = acc[mt][nt];
        uint2 w;
        w.x = pk2(fmaxf(v[0], 0.f), fmaxf(v[1], 0.f));
        w.y = pk2(fmaxf(v[2], 0.f), fmaxf(v[3], 0.f));
        int n = wn * 32 + nt * 16 + ln;
        int m = wm * 64 + mt * 16 + quad * 4;
        *(uint2*)&hw[n * LROW + m] = w;
      }
    }
    if (stager && t < Tt - 1){
      *(unsigned*)&hw[sn * LROW + 256] = pk2(xa, xb);
      hw[sn * LROW + 258] = (short)f2bf(xc);
    }

    __syncthreads();   // h(t+1)/x(t+1) visible; next step reads other buffer
  }

  // ---- epilogue: out^T = W_d^T h^T + b_d; final h is in buf[Tt&1] = buf[1] ----
  const short* hb = &hbuf[Tt & 1][0];
  float4_ oacc[4][2];
  #pragma unroll
  for (int kt = 0; kt < 9; ++kt){
    short8 wf[4];
    #pragma unroll
    for (int mt = 0; mt < 4; ++mt){
      int m = wm * 64 + mt * 16 + ln;
      wf[mt] = *(const short8*)(Wdt + m * KP + kt * 32 + qoff);
    }
    short8 b0 = *(const short8*)&hb[rb0 * LROW + kt * 32 + qoff];
    short8 b1 = *(const short8*)&hb[rb1 * LROW + kt * 32 + qoff];
    #pragma unroll
    for (int mt = 0; mt < 4; ++mt){
      if (kt == 0){
        oacc[mt][0] = __builtin_amdgcn_mfma_f32_16x16x32_bf16(wf[mt], b0, zz, 0, 0, 0);
        oacc[mt][1] = __builtin_amdgcn_mfma_f32_16x16x32_bf16(wf[mt], b1, zz, 0, 0, 0);
      } else {
        oacc[mt][0] = __builtin_amdgcn_mfma_f32_16x16x32_bf16(wf[mt], b0, oacc[mt][0], 0, 0, 0);
        oacc[mt][1] = __builtin_amdgcn_mfma_f32_16x16x32_bf16(wf[mt], b1, oacc[mt][1], 0, 0, 0);
      }
    }
  }

  #pragma unroll
  for (int mt = 0; mt < 4; ++mt){
    #pragma unroll
    for (int nt = 0; nt < 2; ++nt){
      int n = wn * 32 + nt * 16 + ln;
      int m = wm * 64 + mt * 16 + quad * 4;
      *(float4_*)&out[(bbase + n) * Dd + m] = oacc[mt][nt];
    }
  }
}

extern "C" void kernel_launch(void* const* d_in, const int* in_sizes, int n_in,
                              void* d_out, int out_size, void* d_ws, size_t ws_size,
                              hipStream_t stream){
  const float* x0    = (const float*)d_in[0];
  const float* x1    = (const float*)d_in[1];
  const float* x2    = (const float*)d_in[2];
  const float* W_in  = (const float*)d_in[3];
  const float* U     = (const float*)d_in[4];
  const float* b_rnn = (const float*)d_in[5];
  const float* W_d   = (const float*)d_in[6];
  const float* b_d   = (const float*)d_in[7];

  unsigned short* Ut  = (unsigned short*)d_ws;
  unsigned short* Wdt = Ut + 256 * KP;
  float* out = (float*)d_out;

  build_tables<<<(2 * 256 * KP + 255) / 256, 256, 0, stream>>>(W_in, U, b_rnn, W_d, b_d, Ut, Wdt);
  rnn_main<<<Bsz / NTILE, THR, 0, stream>>>(x0, x1, x2, Ut, Wdt, out);
}

// Round 4
// 214.284 us; speedup vs baseline: 1.3792x; 1.0008x over previous
//
#include <hip/hip_runtime.h>
#include <hip/hip_bf16.h>
#include <stdint.h>

#define Bsz   16384
#define Tt    79
#define Hh    256
#define Dd    256
#define KP    288    // padded K: 256 h-cols + 3 x rows + 1 bias row + 28 zero pad
#define LROW  296    // LDS row stride in bf16 elements (592 B)
#define NTILE 32     // batch rows per block (2 blocks/CU for barrier decoupling)
#define THR   256    // 4 waves: wave w = m-quarter, each 64 m-cols x 32 n-rows

typedef __attribute__((ext_vector_type(8))) short  short8;
typedef __attribute__((ext_vector_type(4))) float  float4_;

__device__ __forceinline__ unsigned short f2bf(float f){
  unsigned u = __float_as_uint(f);
  u += 0x7fffu + ((u >> 16) & 1u);      // RNE
  return (unsigned short)(u >> 16);
}
__device__ __forceinline__ unsigned pk2(float a, float b){
  // v_cvt_pk_bf16_f32 on gfx950 (RNE), single VALU op
  __hip_bfloat162 h = __float22bfloat162_rn(make_float2(a, b));
  return *(unsigned*)&h;
}

__global__ void build_tables(const float* __restrict__ W_in,
                             const float* __restrict__ U,
                             const float* __restrict__ b_rnn,
                             const float* __restrict__ W_d,
                             const float* __restrict__ b_d,
                             unsigned short* __restrict__ Ut,
                             unsigned short* __restrict__ Wdt){
  const int TBL = 256 * KP;
  int idx = blockIdx.x * 256 + threadIdx.x;
  if (idx >= 2 * TBL) return;
  int tb  = idx / TBL;
  int rem = idx - tb * TBL;
  int m = rem / KP;
  int k = rem - m * KP;
  float v = 0.f;
  if (tb == 0){
    if      (k < 256) v = U[k * 256 + m];
    else if (k < 259) v = W_in[(k - 256) * 256 + m];
    else if (k == 259) v = b_rnn[m];
  } else {
    if      (k < 256) v = W_d[k * 256 + m];
    else if (k == 259) v = b_d[m];
  }
  unsigned short o = f2bf(v);
  if (tb == 0) Ut[rem] = o; else Wdt[rem] = o;
}

// 512 blocks x 256 threads = 2 blocks/CU (two independent barrier domains per
// CU: while block A drains into __syncthreads, block B's waves issue MFMA).
// Each block owns 32 batch rows; h^T (32 x 288 bf16, double-buffered) in LDS.
// Wave w = m-quarter (0..3): 64 h-cols (4 MFMA tiles) x 32 batch rows (2 tiles).
// A-fragments (U^T + folded W_in/b_rnn): 36 x short8, loop-invariant in regs.
__global__ __launch_bounds__(THR, 2) void rnn_main(
    const float* __restrict__ x0,
    const float* __restrict__ x1,
    const float* __restrict__ x2,
    const unsigned short* __restrict__ Ut,
    const unsigned short* __restrict__ Wdt,
    float* __restrict__ out){
  __shared__ __align__(16) short hbuf[2][NTILE * LROW];

  const int tid  = threadIdx.x;
  const int lane = tid & 63;
  const int wm   = tid >> 6;    // m-quarter 0..3
  const int quad = lane >> 4;
  const int ln   = lane & 15;
  const int qoff = quad * 8;
  const int bbase = blockIdx.x * NTILE;
  const int rb0 = ln;
  const int rb1 = ln + 16;

  // ---- zero both LDS buffers (h0 = 0, pad rows = 0) ----
  {
    int4* p = (int4*)&hbuf[0][0];
    const int tot = 2 * NTILE * LROW * 2 / 16;
    int4 z = make_int4(0, 0, 0, 0);
    for (int i = tid; i < tot; i += THR) p[i] = z;
  }
  __syncthreads();

  // bias row (k=259) = 1.0 bf16 in BOTH buffers (never overwritten)
  if (tid < NTILE){
    hbuf[0][tid * LROW + 259] = (short)0x3F80;
    hbuf[1][tid * LROW + 259] = (short)0x3F80;
  }

  // x rows for step t=0 (original time index T-1) into buf 0
  const bool stager = (wm == 0) && (lane < NTILE);
  const int  sn  = lane & (NTILE - 1);
  const int  sgb = bbase + sn;
  if (stager){
    int tr = Tt - 1;
    float a = x0[sgb * Tt + tr];
    float b = x1[sgb * Tt + tr];
    float c = x2[sgb * Tt + tr];
    *(unsigned*)&hbuf[0][sn * LROW + 256] = pk2(a, b);
    hbuf[0][sn * LROW + 258] = (short)f2bf(c);
  }

  // ---- preload A fragments: 4 mt x 9 kt = 36 short8 ----
  short8 afr[4][9];
  #pragma unroll
  for (int mt = 0; mt < 4; ++mt){
    const unsigned short* p = Ut + (wm * 64 + mt * 16 + ln) * KP + qoff;
    #pragma unroll
    for (int kt = 0; kt < 9; ++kt){
      afr[mt][kt] = *(const short8*)(p + kt * 32);
    }
  }

  __syncthreads();

  const float4_ zz = {0.f, 0.f, 0.f, 0.f};
  float4_ acc[4][2];

  // ---- 79 recurrence steps, ONE barrier each (double-buffered h) ----
  #pragma unroll 1
  for (int t = 0; t < Tt; ++t){
    // prefetch x for step t+1 (latency hidden under the K-loop)
    float xa = 0.f, xb = 0.f, xc = 0.f;
    if (stager && t < Tt - 1){
      int tr = Tt - 2 - t;
      xa = x0[sgb * Tt + tr];
      xb = x1[sgb * Tt + tr];
      xc = x2[sgb * Tt + tr];
    }

    const short* hb = &hbuf[t & 1][0];
    short*       hw = &hbuf[(t + 1) & 1][0];

    #pragma unroll
    for (int kt = 0; kt < 9; ++kt){
      short8 b0 = *(const short8*)&hb[rb0 * LROW + kt * 32 + qoff];
      short8 b1 = *(const short8*)&hb[rb1 * LROW + kt * 32 + qoff];
      #pragma unroll
      for (int mt = 0; mt < 4; ++mt){
        if (kt == 0){
          acc[mt][0] = __builtin_amdgcn_mfma_f32_16x16x32_bf16(afr[mt][0], b0, zz, 0, 0, 0);
          acc[mt][1] = __builtin_amdgcn_mfma_f32_16x16x32_bf16(afr[mt][0], b1, zz, 0, 0, 0);
        } else {
          acc[mt][0] = __builtin_amdgcn_mfma_f32_16x16x32_bf16(afr[mt][kt], b0, acc[mt][0], 0, 0, 0);
          acc[mt][1] = __builtin_amdgcn_mfma_f32_16x16x32_bf16(afr[mt][kt], b1, acc[mt][1], 0, 0, 0);
        }
      }
    }

    // relu + pack (v_cvt_pk_bf16_f32), write h(t+1) into the OTHER buffer
    #pragma unroll
    for (int mt = 0; mt < 4; ++mt){
      #pragma unroll
      for (int nt = 0; nt < 2; ++nt){
        float4_ v = acc[mt][nt];
        uint2 w;
        w.x = pk2(fmaxf(v[0], 0.f), fmaxf(v[1], 0.f));
        w.y = pk2(fmaxf(v[2], 0.f), fmaxf(v[3], 0.f));
        int n = nt * 16 + ln;
        int m = wm * 64 + mt * 16 + quad * 4;
        *(uint2*)&hw[n * LROW + m] = w;
      }
    }
    if (stager && t < Tt - 1){
      *(unsigned*)&hw[sn * LROW + 256] = pk2(xa, xb);
      hw[sn * LROW + 258] = (short)f2bf(xc);
    }

    __syncthreads();   // h(t+1)/x(t+1) visible; next step reads other buffer
  }

  // ---- epilogue: out^T = W_d^T h^T + b_d; final h is in buf[Tt&1] = buf[1] ----
  const short* hb = &hbuf[Tt & 1][0];
  float4_ oacc[4][2];
  #pragma unroll
  for (int kt = 0; kt < 9; ++kt){
    short8 wf[4];
    #pragma unroll
    for (int mt = 0; mt < 4; ++mt){
      int m = wm * 64 + mt * 16 + ln;
      wf[mt] = *(const short8*)(Wdt + m * KP + kt * 32 + qoff);
    }
    short8 b0 = *(const short8*)&hb[rb0 * LROW + kt * 32 + qoff];
    short8 b1 = *(const short8*)&hb[rb1 * LROW + kt * 32 + qoff];
    #pragma unroll
    for (int mt = 0; mt < 4; ++mt){
      if (kt == 0){
        oacc[mt][0] = __builtin_amdgcn_mfma_f32_16x16x32_bf16(wf[mt], b0, zz, 0, 0, 0);
        oacc[mt][1] = __builtin_amdgcn_mfma_f32_16x16x32_bf16(wf[mt], b1, zz, 0, 0, 0);
      } else {
        oacc[mt][0] = __builtin_amdgcn_mfma_f32_16x16x32_bf16(wf[mt], b0, oacc[mt][0], 0, 0, 0);
        oacc[mt][1] = __builtin_amdgcn_mfma_f32_16x16x32_bf16(wf[mt], b1, oacc[mt][1], 0, 0, 0);
      }
    }
  }

  #pragma unroll
  for (int mt = 0; mt < 4; ++mt){
    #pragma unroll
    for (int nt = 0; nt < 2; ++nt){
      int n = nt * 16 + ln;
      int m = wm * 64 + mt * 16 + quad * 4;
      *(float4_*)&out[(bbase + n) * Dd + m] = oacc[mt][nt];
    }
  }
}

extern "C" void kernel_launch(void* const* d_in, const int* in_sizes, int n_in,
                              void* d_out, int out_size, void* d_ws, size_t ws_size,
                              hipStream_t stream){
  const float* x0    = (const float*)d_in[0];
  const float* x1    = (const float*)d_in[1];
  const float* x2    = (const float*)d_in[2];
  const float* W_in  = (const float*)d_in[3];
  const float* U     = (const float*)d_in[4];
  const float* b_rnn = (const float*)d_in[5];
  const float* W_d   = (const float*)d_in[6];
  const float* b_d   = (const float*)d_in[7];

  unsigned short* Ut  = (unsigned short*)d_ws;
  unsigned short* Wdt = Ut + 256 * KP;
  float* out = (float*)d_out;

  build_tables<<<(2 * 256 * KP + 255) / 256, 256, 0, stream>>>(W_in, U, b_rnn, W_d, b_d, Ut, Wdt);
  rnn_main<<<Bsz / NTILE, THR, 0, stream>>>(x0, x1, x2, Ut, Wdt, out);
}